// Round 22
// baseline (391.711 us; speedup 1.0000x reference)
//
#include <hip/hip_runtime.h>
#include <hip/hip_bf16.h>
#include <cstddef>
#include <cstdint>

// WindowAttention3D for MI355X (gfx950). Inputs f32, output f32.
// FULL (ws>=~255MB): k_qkv single-buffer GEMM (43KB LDS -> 3 blocks/CU,
//   24 waves) reading f32 x directly, BMF generation fused as prefix blocks;
//   k_attn 1 block/window, head-ahead prefetch, lgkm-only barriers;
//   k2_proj2 counted-vmcnt dbuf. MID (ws>=~80MB): k1_attn + k2_proj. MONO.
// r22: occupancy experiment — r19/r21's dbuf k_qkv2 (82KB, 2 blk/CU) was
//   latency-bound at 16 waves/CU; single-buf structure trades pipeline depth
//   for +50% TLP.

using bf16 = __hip_bfloat16;
typedef short v8s __attribute__((ext_vector_type(8)));
typedef short v4s __attribute__((ext_vector_type(4)));
typedef float v4f __attribute__((ext_vector_type(4)));

static constexpr int    NTOK   = 99;
static constexpr int    CDIM   = 384;
static constexpr int    NHEAD  = 12;
static constexpr int    NROWS  = 101376;             // 1024*99
static constexpr size_t PLANE  = (size_t)NROWS * 32;
static constexpr float  SCALEF = 0.17677669529663687f;

__device__ __forceinline__ v4f mfma16x16x32(v8s a, v8s b, v4f c) {
  return __builtin_amdgcn_mfma_f32_16x16x32_bf16(a, b, c, 0, 0, 0);
}
__device__ __forceinline__ short f2bf(float f) {
  bf16 h = __float2bfloat16(f);
  return *reinterpret_cast<short*>(&h);
}
__device__ __forceinline__ float bf2f(short s) {
  bf16 h = *reinterpret_cast<bf16*>(&s);
  return __bfloat162float(h);
}

#if defined(__has_builtin)
#if __has_builtin(__builtin_amdgcn_global_load_lds)
#define HAS_GLL 1
#endif
#endif
#ifndef HAS_GLL
#define HAS_GLL 0
#endif

__device__ __forceinline__ void gload_lds16(const bf16* gsrc, bf16* ldst, int lane) {
#if HAS_GLL
  __builtin_amdgcn_global_load_lds(
      (const __attribute__((address_space(1))) void*)gsrc,
      (__attribute__((address_space(3))) void*)ldst, 16, 0, 0);
#else
  *(v8s*)(ldst + lane * 8) = *(const v8s*)gsrc;
#endif
}

// ---- ws layout ----
static constexpr size_t WT_QKV_OFF = 0;
static constexpr size_t WT_P_OFF   = 884736;
static constexpr size_t BIAS_OFF   = 884736 + 294912;
static constexpr size_t COMMON_END = 1650096;
static constexpr size_t O_WS_OFF   = COMMON_END;
static constexpr size_t WS_MID     = O_WS_OFF + (size_t)NROWS * 384 * 2;
static constexpr size_t BMF_OFF    = COMMON_END;
static constexpr size_t BMF_BYTES  = (size_t)64 * NHEAD * 7 * 7 * 64 * 4 * 2;
static constexpr size_t QKV_OFF    = BMF_OFF + BMF_BYTES;
static constexpr size_t WS_FULL    = QKV_OFF + (size_t)NROWS * 1152 * 2;   // ~254.5MB

static constexpr int PREP_W    = 1152 * 384 + 384 * 384;          // weights only
static constexpr int PREP_BASE = PREP_W + NHEAD * 99 * 99;        // + BIAS (MID)
static constexpr int PREP_BMF2 = 64 * 112 * 112;                  // 802,816
static constexpr int BMF_BLKS  = (PREP_BMF2 + 511) / 512;         // 1568 (div by 8)

// ---------------- BMF generation (fused into k_qkv prefix blocks) -----------
__device__ __forceinline__ void bmf_gen_item(int j2, const float* __restrict__ rpb,
                                             const int* __restrict__ rpi,
                                             const float* __restrict__ mask,
                                             bf16* __restrict__ BMF)
{
  int col = j2 % 112;
  int r2  = j2 / 112;
  int row = r2 % 112;
  int wi  = r2 / 112;
  int w = row >> 4, g = (row >> 2) & 3, jj = row & 3;
  int t = col >> 4, li = col & 15, lane = g * 16 + li;
  bool in = (row >= 1 && row <= 98 && col >= 1 && col <= 98);
  int tix = 0; float mval = 0.f;
  if (in) {
    tix  = rpi[(row - 1) * 98 + (col - 1)];
    mval = mask[((size_t)wi * 98 + (row - 1)) * 98 + (col - 1)];
  }
  size_t base = (((size_t)wi * NHEAD * 7 + w) * 7 + t) * 256 + lane * 4 + jj;
  #pragma unroll
  for (int h = 0; h < NHEAD; ++h) {
    float v;
    if (col > 98)  v = -1e30f;              // baked column mask
    else           v = in ? (rpb[tix * NHEAD + h] + mval) : 0.f;
    BMF[base + (size_t)h * 12544] = __float2bfloat16(v);   // 12544 = 49*256
  }
}

// ---------------- prep: weight transposes (+ BIAS for MID tier) -------------
__global__ void prep_kernel(const float* __restrict__ Wqkv, const float* __restrict__ Wproj,
                            const float* __restrict__ rpb,  const int* __restrict__ rpi,
                            bf16* __restrict__ WtQKV, bf16* __restrict__ WtP,
                            float* __restrict__ BIAS, int do_bias)
{
  int idx = blockIdx.x * 256 + threadIdx.x;
  if (idx < 1152 * 384) {
    int c = idx / 384, k = idx - c * 384;
    WtQKV[idx] = __float2bfloat16(Wqkv[k * 1152 + c]);
  } else if (idx < PREP_W) {
    int j = idx - 1152 * 384;
    int c = j / 384, k = j - c * 384;
    WtP[j] = __float2bfloat16(Wproj[k * 384 + c]);
  } else if (do_bias && idx < PREP_BASE) {
    int j = idx - PREP_W;
    int h = j / (99 * 99), r = j % (99 * 99);
    int nn = r / 99, mm = r % 99;
    float v = 0.f;
    if (nn > 0 && mm > 0) v = rpb[rpi[(nn - 1) * 98 + (mm - 1)] * NHEAD + h];
    BIAS[j] = v;
  }
}

// ================= k_qkv: single-buffer GEMM, f32 A, fused BMF ===============
// 43,008 B LDS -> 3 blocks/CU (24 waves). Round-11 proven structure:
// write A(kc) -> issue gload B(kc) -> prefetch A(kc+1) regs -> sync -> MFMA.
static constexpr int GQB_OFF  = 0;
static constexpr int GQA_OFF  = 24576;
static constexpr int GQ_LDS2  = GQA_OFF + 128 * 72 * 2;   // 43,008
static constexpr int CSTG_LD  = 104;
static constexpr int Q2_BUF   = 40960;        // k2_proj2 buffers (unchanged)
static constexpr int Q2_AOFF  = 24576;

__global__ __launch_bounds__(512)
void k_qkv(const float* __restrict__ x, const bf16* __restrict__ WtQKV,
           bf16* __restrict__ qkv2,
           const float* __restrict__ rpb, const int* __restrict__ rpi,
           const float* __restrict__ mask, bf16* __restrict__ BMF)
{
  __shared__ __align__(16) char smem[GQ_LDS2];
  bf16* B_lds = (bf16*)(smem + GQB_OFF);
  bf16* A_lds = (bf16*)(smem + GQA_OFF);
  bf16* C_stg = (bf16*)(smem);

  // ---- prefix blocks: BMF generation (overlaps with GEMM residency) ----
  if (blockIdx.x < BMF_BLKS) {
    int j2 = blockIdx.x * 512 + threadIdx.x;
    if (j2 < PREP_BMF2) bmf_gen_item(j2, rpb, rpi, mask, BMF);
    return;
  }
  const int bid  = blockIdx.x - BMF_BLKS;           // 0..4751

  const int tid  = threadIdx.x;
  const int wave = tid >> 6;
  const int wm   = wave >> 2;
  const int wn   = wave & 3;
  const int lane = tid & 63;
  const int g    = lane >> 4;
  const int li   = lane & 15;
  const int tile = (bid & 7) * 594 + (bid >> 3);    // 4752 = 8*594
  const int R0   = (tile / 6) * 128;
  const int CN   = (tile % 6) * 192;

  const int arr = tid >> 3, ak8 = tid & 7;

  v4f acc[4][3];
  #pragma unroll
  for (int mi = 0; mi < 4; ++mi)
    #pragma unroll
    for (int ni = 0; ni < 3; ++ni) acc[mi][ni] = (v4f){0.f, 0.f, 0.f, 0.f};

  v4f areg[2][2];
  auto load_areg = [&](int kc) {
    const int k0 = kc * 64;
    #pragma unroll
    for (int p = 0; p < 2; ++p) {
      const float* src = x + (size_t)(R0 + arr + p * 64) * 384 + k0 + ak8 * 8;
      areg[p][0] = *(const v4f*)(src);
      areg[p][1] = *(const v4f*)(src + 4);
    }
  };
  auto write_alds = [&]() {
    #pragma unroll
    for (int p = 0; p < 2; ++p) {
      v8s f;
      #pragma unroll
      for (int j = 0; j < 4; ++j) { f[j] = f2bf(areg[p][0][j]); f[j + 4] = f2bf(areg[p][1][j]); }
      *(v8s*)(A_lds + (arr + p * 64) * 72 + ak8 * 8) = f;
    }
  };

  load_areg(0);

  for (int kc = 0; kc < 6; ++kc) {
    const int k0 = kc * 64;
    write_alds();
    #pragma unroll
    for (int p = 0; p < 3; ++p) {
      int q   = wave * 3 + p;
      int row = q * 8 + (lane >> 3);
      int c   = (lane & 7) ^ (row & 7);
      const bf16* gsrc = WtQKV + (size_t)(CN + row) * 384 + k0 + c * 8;
      gload_lds16(gsrc, B_lds + q * 512, lane);
    }
    if (kc < 5) load_areg(kc + 1);
    __syncthreads();
    #pragma unroll
    for (int ks = 0; ks < 2; ++ks) {
      v8s af[4], bfr[3];
      #pragma unroll
      for (int mi = 0; mi < 4; ++mi)
        af[mi] = *(const v8s*)(A_lds + (wm * 64 + mi * 16 + li) * 72 + ks * 32 + g * 8);
      #pragma unroll
      for (int ni = 0; ni < 3; ++ni) {
        int brow = wn * 48 + ni * 16 + li;
        int sc   = (g + 4 * ks) ^ (brow & 7);
        bfr[ni]  = *(const v8s*)(B_lds + brow * 64 + sc * 8);
      }
      #pragma unroll
      for (int mi = 0; mi < 4; ++mi)
        #pragma unroll
        for (int ni = 0; ni < 3; ++ni)
          acc[mi][ni] = mfma16x16x32(af[mi], bfr[ni], acc[mi][ni]);
    }
    __syncthreads();
  }

  // ---- two-pass epilogue: acc -> C_stg (halves) -> coalesced plane stores --
  const float scale = (CN < 384) ? SCALEF : 1.f;
  const int r_ep = tid >> 2, d8 = tid & 3;
  #pragma unroll
  for (int half = 0; half < 2; ++half) {
    __syncthreads();
    if ((wn >> 1) == half) {
      #pragma unroll
      for (int mi = 0; mi < 4; ++mi)
        #pragma unroll
        for (int ni = 0; ni < 3; ++ni)
          #pragma unroll
          for (int j = 0; j < 4; ++j)
            C_stg[(wm * 64 + mi * 16 + g * 4 + j) * CSTG_LD + (wn & 1) * 48 + ni * 16 + li] =
                __float2bfloat16(acc[mi][ni][j] * scale);
    }
    __syncthreads();
    #pragma unroll
    for (int cidx = 0; cidx < 3; ++cidx) {
      int c_global = CN + half * 96 + cidx * 32;
      int seg = c_global / 384, hh = (c_global % 384) >> 5;
      bf16* plane = qkv2 + (size_t)(hh * 3 + seg) * PLANE;
      v8s val = *(const v8s*)(C_stg + r_ep * CSTG_LD + cidx * 32 + d8 * 8);
      *(v8s*)(plane + (size_t)(R0 + r_ep) * 32 + d8 * 8) = val;
    }
  }
}

// ================= k_attn v4: 12 heads/block, full head-ahead prefetch =======
static constexpr int A_VT_LD = 136;
static constexpr int A_P_LD  = 136;
static constexpr int A_OFF_V = 0;
static constexpr int A_OFF_P = A_OFF_V + 32 * A_VT_LD * 2;
static constexpr int A_LDS   = A_OFF_P + 112 * A_P_LD * 2;   // 39,168 B

__global__ __launch_bounds__(448)
void k_attn(const bf16* __restrict__ BMF, bf16* __restrict__ qkv2)
{
  __shared__ __align__(16) char smem[A_LDS];
  bf16* vT_lds = (bf16*)(smem + A_OFF_V);
  bf16* P_lds  = (bf16*)(smem + A_OFF_P);

  const int b    = blockIdx.x;
  const int tid  = threadIdx.x;
  const int wave = tid >> 6;
  const int lane = tid & 63;
  const int g    = lane >> 4;
  const int li   = lane & 15;
  const int wi   = b & 63;

  const int r = tid >> 2, l4 = tid & 3;
  const size_t voff = ((size_t)b * NTOK + ((r > 98) ? 98 : r)) * 32 + l4 * 8;

  const int qrow = (16 * wave + li > 98) ? 98 : 16 * wave + li;
  const size_t qoff = ((size_t)b * NTOK + qrow) * 32 + g * 8;
  int koff[7];
  #pragma unroll
  for (int t = 0; t < 7; ++t) {
    int krow = 16 * t + li; if (krow > 98) krow = 98;
    koff[t] = (b * NTOK + krow) * 32 + g * 8;
  }
  const bf16* bmw = BMF + ((size_t)(wi * NHEAD) * 7 + wave) * 7 * 256 + lane * 4;

  // V(h0) load in flight while we zero LDS
  v8s pv = *(const v8s*)(qkv2 + (size_t)2 * PLANE + voff);

  for (int z = tid; z < A_LDS / 16; z += 448)
    *(v8s*)(smem + z * 16) = (v8s){0, 0, 0, 0, 0, 0, 0, 0};
  __syncthreads();

  if (r < NTOK) {
    #pragma unroll
    for (int e = 0; e < 8; ++e)
      *(short*)(vT_lds + (l4 * 8 + e) * A_VT_LD + r) = pv[e];
  }

  // first head's K/Q fragments + BMF tile
  v8s kf[7], qf;
  v4s bmr[7];
  {
    const bf16* kp = qkv2 + (size_t)1 * PLANE;
    #pragma unroll
    for (int t = 0; t < 7; ++t) kf[t] = *(const v8s*)(kp + koff[t]);
    qf = *(const v8s*)(qkv2 + qoff);
    #pragma unroll
    for (int t = 0; t < 7; ++t)
      bmr[t] = *(const v4s*)(bmw + t * 256);
  }
  __syncthreads();

  for (int h = 0; h < NHEAD; ++h) {
    // S = q k^T (consumes kf/qf before prefetch overwrites)
    v4f sacc[7];
    #pragma unroll
    for (int t = 0; t < 7; ++t) {
      v4f z = (v4f){0.f, 0.f, 0.f, 0.f};
      sacc[t] = mfma16x16x32(qf, kf[t], z);
    }

    // prefetch next head's K/Q/V (fly during softmax + PV)
    v8s nv;
    if (h < NHEAD - 1) {
      const bf16* kp = qkv2 + (size_t)((h + 1) * 3 + 1) * PLANE;
      #pragma unroll
      for (int t = 0; t < 7; ++t) kf[t] = *(const v8s*)(kp + koff[t]);
      qf = *(const v8s*)(qkv2 + (size_t)((h + 1) * 3) * PLANE + qoff);
      nv = *(const v8s*)(qkv2 + (size_t)((h + 1) * 3 + 2) * PLANE + voff);
    }

    // bias + mask, unconditional (pad cols carry -1e30); consumes bmr(h)
    #pragma unroll
    for (int t = 0; t < 7; ++t)
      #pragma unroll
      for (int j = 0; j < 4; ++j)
        sacc[t][j] += bf2f(bmr[t][j]);

    // prefetch next head's BMF tile
    if (h < NHEAD - 1) {
      const bf16* bmb = bmw + (size_t)(h + 1) * 12544;
      #pragma unroll
      for (int t = 0; t < 7; ++t)
        bmr[t] = *(const v4s*)(bmb + t * 256);
    }

    // softmax (rows live in 16-lane groups)
    float linv[4];
    #pragma unroll
    for (int j = 0; j < 4; ++j) {
      float m = -1e30f;
      #pragma unroll
      for (int t = 0; t < 7; ++t) m = fmaxf(m, sacc[t][j]);
      m = fmaxf(m, __shfl_xor(m, 1));
      m = fmaxf(m, __shfl_xor(m, 2));
      m = fmaxf(m, __shfl_xor(m, 4));
      m = fmaxf(m, __shfl_xor(m, 8));
      float l = 0.f;
      #pragma unroll
      for (int t = 0; t < 7; ++t) {
        float p = __expf(sacc[t][j] - m);
        sacc[t][j] = p;
        l += p;
      }
      l += __shfl_xor(l, 1);
      l += __shfl_xor(l, 2);
      l += __shfl_xor(l, 4);
      l += __shfl_xor(l, 8);
      linv[j] = 1.f / l;
      int row = 16 * wave + g * 4 + j;
      #pragma unroll
      for (int t = 0; t < 7; ++t)
        P_lds[row * A_P_LD + 16 * t + li] = __float2bfloat16(sacc[t][j]);
    }
    // PV: pure MFMA over padded k=0..127
    v4f oacc[2];
    oacc[0] = (v4f){0.f, 0.f, 0.f, 0.f};
    oacc[1] = (v4f){0.f, 0.f, 0.f, 0.f};
    #pragma unroll
    for (int ks = 0; ks < 4; ++ks) {
      v8s ap = *(const v8s*)(P_lds + (16 * wave + li) * A_P_LD + ks * 32 + g * 8);
      #pragma unroll
      for (int t = 0; t < 2; ++t) {
        v8s bv = *(const v8s*)(vT_lds + (16 * t + li) * A_VT_LD + ks * 32 + g * 8);
        oacc[t] = mfma16x16x32(ap, bv, oacc[t]);
      }
    }
    // O -> dead q-plane of head h (stores NOT drained at barriers below)
    bf16* oplane = qkv2 + (size_t)(h * 3) * PLANE;
    #pragma unroll
    for (int t = 0; t < 2; ++t)
      #pragma unroll
      for (int j = 0; j < 4; ++j) {
        int row = 16 * wave + g * 4 + j;
        if (row < NTOK)
          oplane[((size_t)b * NTOK + row) * 32 + 16 * t + li] =
              __float2bfloat16(oacc[t][j] * linv[j]);
      }

    // LDS-only barrier: all waves' ds_reads of vT(h)/P(h) complete
    asm volatile("s_waitcnt lgkmcnt(0)" ::: "memory");
    asm volatile("s_barrier" ::: "memory");
    if (h < NHEAD - 1) {
      if (r < NTOK) {
        #pragma unroll
        for (int e = 0; e < 8; ++e)
          *(short*)(vT_lds + (l4 * 8 + e) * A_VT_LD + r) = nv[e];
      }
      asm volatile("s_waitcnt lgkmcnt(0)" ::: "memory");
      asm volatile("s_barrier" ::: "memory");
    }
  }
}

// ================= k2_proj2: counted-vmcnt dbuf proj (FULL tier) =============
__global__ __launch_bounds__(512)
void k2_proj2(const bf16* __restrict__ O_src, const bf16* __restrict__ WtP,
              const float* __restrict__ bproj, float* __restrict__ out)
{
  __shared__ __align__(16) char smem[2 * Q2_BUF];

  const int tid  = threadIdx.x;
  const int wave = tid >> 6;
  const int wm   = wave >> 2;
  const int wn   = wave & 3;
  const int lane = tid & 63;
  const int g    = lane >> 4;
  const int li   = lane & 15;
  const int tile = (blockIdx.x & 7) * 198 + (blockIdx.x >> 3);
  const int R0   = (tile >> 1) * 128;
  const int CN   = (tile & 1) * 192;

  v4f acc[4][3];
  #pragma unroll
  for (int mi = 0; mi < 4; ++mi)
    #pragma unroll
    for (int ni = 0; ni < 3; ++ni) acc[mi][ni] = (v4f){0.f, 0.f, 0.f, 0.f};

  auto stage = [&](int kc, int buf) {
    const int k0 = kc * 64;
    bf16* Wl = (bf16*)(smem + buf * Q2_BUF);
    bf16* Ol = (bf16*)(smem + buf * Q2_BUF + Q2_AOFF);
    #pragma unroll
    for (int p = 0; p < 3; ++p) {
      int q = wave * 3 + p;
      int row = q * 8 + (lane >> 3);
      int c = (lane & 7) ^ (row & 7);
      gload_lds16(WtP + (size_t)(CN + row) * CDIM + k0 + c * 8, Wl + q * 512, lane);
    }
    #pragma unroll
    for (int p = 0; p < 2; ++p) {
      int q = wave * 2 + p;
      int row = q * 8 + (lane >> 3);
      int c = (lane & 7) ^ (row & 7);
      int kk = k0 + c * 8, hh = kk >> 5, d = kk & 31;
      gload_lds16(O_src + (size_t)(hh * 3) * PLANE + (size_t)(R0 + row) * 32 + d,
                  Ol + q * 512, lane);
    }
  };

  stage(0, 0);
  for (int kc = 0; kc < 6; ++kc) {
    if (kc < 5) {
      stage(kc + 1, (kc + 1) & 1);
      asm volatile("s_waitcnt vmcnt(5)" ::: "memory");
    } else {
      asm volatile("s_waitcnt vmcnt(0)" ::: "memory");
    }
    __builtin_amdgcn_s_barrier();
    __builtin_amdgcn_sched_barrier(0);
    const bf16* Wl = (const bf16*)(smem + (kc & 1) * Q2_BUF);
    const bf16* Ol = (const bf16*)(smem + (kc & 1) * Q2_BUF + Q2_AOFF);
    #pragma unroll
    for (int ks = 0; ks < 2; ++ks) {
      v8s af[4], bfr[3];
      #pragma unroll
      for (int mi = 0; mi < 4; ++mi) {
        int arow = wm * 64 + mi * 16 + li;
        int sc   = (4 * ks + g) ^ (arow & 7);
        af[mi] = *(const v8s*)(Ol + arow * 64 + sc * 8);
      }
      #pragma unroll
      for (int ni = 0; ni < 3; ++ni) {
        int brow = wn * 48 + ni * 16 + li;
        int sc   = (4 * ks + g) ^ (brow & 7);
        bfr[ni] = *(const v8s*)(Wl + brow * 64 + sc * 8);
      }
      #pragma unroll
      for (int mi = 0; mi < 4; ++mi)
        #pragma unroll
        for (int ni = 0; ni < 3; ++ni)
          acc[mi][ni] = mfma16x16x32(af[mi], bfr[ni], acc[mi][ni]);
    }
    __builtin_amdgcn_sched_barrier(0);
    __builtin_amdgcn_s_barrier();
  }

  const size_t OUT2 = (size_t)1024 * 98 * CDIM;
  #pragma unroll
  for (int mi = 0; mi < 4; ++mi)
    #pragma unroll
    for (int ni = 0; ni < 3; ++ni) {
      int col = CN + wn * 48 + ni * 16 + li;
      float bb = bproj[col];
      #pragma unroll
      for (int j = 0; j < 4; ++j) {
        int rr = R0 + wm * 64 + mi * 16 + g * 4 + j;
        int b = rr / 99, n = rr - b * 99;
        float v = acc[mi][ni][j] + bb;
        if (n == 0) out[OUT2 + (size_t)b * CDIM + col] = v;
        else        out[((size_t)b * 98 + (n - 1)) * CDIM + col] = v;
      }
    }
}

// ================= k2_proj: MID-tier linear-O version ========================
static constexpr int K2_LD   = 72;
static constexpr int K2_OFFW = 0;
static constexpr int K2_OFFO = 192 * K2_LD * 2;
static constexpr int K2_LDS  = K2_OFFO + 128 * K2_LD * 2;

__global__ __launch_bounds__(512)
void k2_proj(const bf16* __restrict__ O_src, const bf16* __restrict__ WtP,
             const float* __restrict__ bproj, float* __restrict__ out)
{
  __shared__ __align__(16) char smem[K2_LDS];
  bf16* W_lds = (bf16*)(smem + K2_OFFW);
  bf16* O_lds = (bf16*)(smem + K2_OFFO);

  const int tid  = threadIdx.x;
  const int wave = tid >> 6;
  const int wm   = wave >> 2;
  const int wn   = wave & 3;
  const int lane = tid & 63;
  const int g    = lane >> 4;
  const int li   = lane & 15;
  const int tile = (blockIdx.x & 7) * 198 + (blockIdx.x >> 3);
  const int R0   = (tile >> 1) * 128;
  const int CN   = (tile & 1) * 192;

  v4f acc[4][3];
  #pragma unroll
  for (int mi = 0; mi < 4; ++mi)
    #pragma unroll
    for (int ni = 0; ni < 3; ++ni) acc[mi][ni] = (v4f){0.f, 0.f, 0.f, 0.f};

  for (int kc = 0; kc < 6; ++kc) {
    const int k0 = kc * 64;
    #pragma unroll
    for (int p = 0; p < 3; ++p) {
      int it = tid + p * 512, rr = it >> 3, k8 = it & 7;
      *(v8s*)(W_lds + rr * K2_LD + k8 * 8) =
          *(const v8s*)(WtP + (size_t)(CN + rr) * CDIM + k0 + k8 * 8);
    }
    #pragma unroll
    for (int p = 0; p < 2; ++p) {
      int it = tid + p * 512, rr = it >> 3, k8 = it & 7;
      *(v8s*)(O_lds + rr * K2_LD + k8 * 8) =
          *(const v8s*)(O_src + (size_t)(R0 + rr) * 384 + k0 + k8 * 8);
    }
    __syncthreads();
    #pragma unroll
    for (int ks = 0; ks < 2; ++ks) {
      v8s af[4], bfr[3];
      #pragma unroll
      for (int mi = 0; mi < 4; ++mi)
        af[mi] = *(const v8s*)(O_lds + (wm * 64 + mi * 16 + li) * K2_LD + ks * 32 + g * 8);
      #pragma unroll
      for (int ni = 0; ni < 3; ++ni)
        bfr[ni] = *(const v8s*)(W_lds + (wn * 48 + ni * 16 + li) * K2_LD + ks * 32 + g * 8);
      #pragma unroll
      for (int mi = 0; mi < 4; ++mi)
        #pragma unroll
        for (int ni = 0; ni < 3; ++ni)
          acc[mi][ni] = mfma16x16x32(af[mi], bfr[ni], acc[mi][ni]);
    }
    __syncthreads();
  }

  const size_t OUT2 = (size_t)1024 * 98 * CDIM;
  #pragma unroll
  for (int mi = 0; mi < 4; ++mi)
    #pragma unroll
    for (int ni = 0; ni < 3; ++ni) {
      int col = CN + wn * 48 + ni * 16 + li;
      float bb = bproj[col];
      #pragma unroll
      for (int j = 0; j < 4; ++j) {
        int rr = R0 + wm * 64 + mi * 16 + g * 4 + j;
        int b = rr / 99, n = rr - b * 99;
        float v = acc[mi][ni][j] + bb;
        if (n == 0) out[OUT2 + (size_t)b * CDIM + col] = v;
        else        out[((size_t)b * 98 + (n - 1)) * CDIM + col] = v;
      }
    }
}

// ================= MID tier: round-5 proven k1_attn =========================
static constexpr int QK_LD = 40;
static constexpr int VT_LD = 136;
static constexpr int P_LD  = 136;
static constexpr int WS_LD = 104;
static constexpr int K1_OFF_Q = 0;
static constexpr int K1_OFF_K = K1_OFF_Q + 112 * QK_LD * 2;
static constexpr int K1_OFF_V = K1_OFF_K + 112 * QK_LD * 2;
static constexpr int K1_OFF_P = K1_OFF_V + 32  * VT_LD * 2;
static constexpr int K1_OFF_W = K1_OFF_P + 112 * P_LD  * 2;
static constexpr int K1_LDS   = K1_OFF_W + 96 * WS_LD * 2;

__global__ __launch_bounds__(512)
void k1_attn(const float* __restrict__ x, const float* __restrict__ mask,
             const float* __restrict__ BIAS, const bf16* __restrict__ WtQKV,
             bf16* __restrict__ O_ws)
{
  __shared__ __align__(16) char smem[K1_LDS];
  bf16* q_lds  = (bf16*)(smem + K1_OFF_Q);
  bf16* k_lds  = (bf16*)(smem + K1_OFF_K);
  bf16* vT_lds = (bf16*)(smem + K1_OFF_V);
  bf16* P_lds  = (bf16*)(smem + K1_OFF_P);
  bf16* w_lds  = (bf16*)(smem + K1_OFF_W);

  const int b    = blockIdx.x;
  const int tid  = threadIdx.x;
  const int wave = tid >> 6;
  const int lane = tid & 63;
  const int g    = lane >> 4;
  const int li   = lane & 15;
  const int wi   = b & 63;

  v8s afr[12];
  if (wave < 7) {
    int arow = 16 * wave + li; if (arow > 98) arow = 98;
    const float* xb = x + ((size_t)b * NTOK + arow) * CDIM + g * 8;
    #pragma unroll
    for (int s = 0; s < 12; ++s) {
      v4f x0 = *(const v4f*)(xb + s * 32);
      v4f x1 = *(const v4f*)(xb + s * 32 + 4);
      v8s f;
      #pragma unroll
      for (int j = 0; j < 4; ++j) { f[j] = f2bf(x0[j]); f[j + 4] = f2bf(x1[j]); }
      afr[s] = f;
    }
  }

  for (int h = 0; h < NHEAD; ++h) {
    v4f qacc[6];
    #pragma unroll
    for (int t = 0; t < 6; ++t) qacc[t] = (v4f){0.f, 0.f, 0.f, 0.f};
    #pragma unroll
    for (int c4 = 0; c4 < 4; ++c4) {
      for (int idx = tid; idx < 96 * 12; idx += 512) {
        int rr = idx / 12, ch = idx - rr * 12;
        int cg = (rr < 32) ? (h * 32 + rr)
               : (rr < 64) ? (CDIM + h * 32 + rr - 32)
                           : (2 * CDIM + h * 32 + rr - 64);
        *(v8s*)(w_lds + rr * WS_LD + ch * 8) =
            *(const v8s*)(WtQKV + (size_t)cg * CDIM + c4 * 96 + ch * 8);
      }
      __syncthreads();
      if (wave < 7) {
        #pragma unroll
        for (int ss = 0; ss < 3; ++ss) {
          const int s = c4 * 3 + ss;
          #pragma unroll
          for (int t = 0; t < 6; ++t) {
            v8s bw = *(const v8s*)(w_lds + (16 * t + li) * WS_LD + ss * 32 + g * 8);
            qacc[t] = mfma16x16x32(afr[s], bw, qacc[t]);
          }
        }
      }
      __syncthreads();
    }
    if (wave < 7) {
      #pragma unroll
      for (int t = 0; t < 6; ++t) {
        #pragma unroll
        for (int j = 0; j < 4; ++j) {
          int row = 16 * wave + g * 4 + j;
          int col = 16 * (t & 1) + li;
          float v = qacc[t][j];
          if (t < 2)      q_lds[row * QK_LD + col] = __float2bfloat16(v * SCALEF);
          else if (t < 4) k_lds[row * QK_LD + col] = __float2bfloat16(v);
          else            vT_lds[col * VT_LD + row] = __float2bfloat16(v);
        }
      }
    }
    vT_lds[(tid >> 4) * VT_LD + 112 + (tid & 15)] = __float2bfloat16(0.f);
    __syncthreads();

    if (wave < 7) {
      v8s aq = *(const v8s*)(q_lds + (16 * wave + li) * QK_LD + g * 8);
      v4f sacc[7];
      #pragma unroll
      for (int t = 0; t < 7; ++t) {
        v8s bk = *(const v8s*)(k_lds + (16 * t + li) * QK_LD + g * 8);
        v4f z = (v4f){0.f, 0.f, 0.f, 0.f};
        sacc[t] = mfma16x16x32(aq, bk, z);
      }
      #pragma unroll
      for (int t = 0; t < 7; ++t) {
        int col = 16 * t + li;
        #pragma unroll
        for (int j = 0; j < 4; ++j) {
          int row = 16 * wave + g * 4 + j;
          float s = sacc[t][j];
          if (col >= NTOK) s = -1e30f;
          else if (row < NTOK) {
            s += BIAS[(h * NTOK + row) * NTOK + col];
            if (row > 0 && col > 0)
              s += mask[((size_t)wi * 98 + (row - 1)) * 98 + (col - 1)];
          }
          sacc[t][j] = s;
        }
      }
      float linv[4];
      #pragma unroll
      for (int j = 0; j < 4; ++j) {
        float m = -1e30f;
        #pragma unroll
        for (int t = 0; t < 7; ++t) m = fmaxf(m, sacc[t][j]);
        m = fmaxf(m, __shfl_xor(m, 1));
        m = fmaxf(m, __shfl_xor(m, 2));
        m = fmaxf(m, __shfl_xor(m, 4));
        m = fmaxf(m, __shfl_xor(m, 8));
        float l = 0.f;
        #pragma unroll
        for (int t = 0; t < 7; ++t) {
          float p = __expf(sacc[t][j] - m);
          sacc[t][j] = p;
          l += p;
        }
        l += __shfl_xor(l, 1);
        l += __shfl_xor(l, 2);
        l += __shfl_xor(l, 4);
        l += __shfl_xor(l, 8);
        linv[j] = 1.f / l;
        int row = 16 * wave + g * 4 + j;
        #pragma unroll
        for (int t = 0; t < 7; ++t)
          P_lds[row * P_LD + 16 * t + li] = __float2bfloat16(sacc[t][j]);
        P_lds[row * P_LD + 112 + li] = __float2bfloat16(0.f);
      }
      v4f oacc[2];
      oacc[0] = (v4f){0.f, 0.f, 0.f, 0.f};
      oacc[1] = (v4f){0.f, 0.f, 0.f, 0.f};
      #pragma unroll
      for (int ks = 0; ks < 4; ++ks) {
        v8s ap = *(const v8s*)(P_lds + (16 * wave + li) * P_LD + ks * 32 + g * 8);
        #pragma unroll
        for (int t = 0; t < 2; ++t) {
          v8s bv = *(const v8s*)(vT_lds + (16 * t + li) * VT_LD + ks * 32 + g * 8);
          oacc[t] = mfma16x16x32(ap, bv, oacc[t]);
        }
      }
      #pragma unroll
      for (int t = 0; t < 2; ++t) {
        #pragma unroll
        for (int j = 0; j < 4; ++j) {
          int row = 16 * wave + g * 4 + j;
          if (row < NTOK)
            O_ws[((size_t)b * 99 + row) * CDIM + h * 32 + 16 * t + li] =
                __float2bfloat16(oacc[t][j] * linv[j]);
        }
      }
    }
    __syncthreads();
  }
}

// ================= MONO tier: round-4 proven =================================
static constexpr int M_O_LD = 392;
static constexpr int M_OFF_O = 0;
static constexpr int M_OFF_Q = M_OFF_O + 99  * M_O_LD * 2;
static constexpr int M_OFF_K = M_OFF_Q + 112 * QK_LD * 2;
static constexpr int M_OFF_V = M_OFF_K + 112 * QK_LD * 2;
static constexpr int M_OFF_P = M_OFF_V + 32  * VT_LD * 2;
static constexpr int M_OFF_W = M_OFF_P + 112 * P_LD  * 2;
static constexpr int M_LDS   = M_OFF_W + 96 * WS_LD * 2;

__global__ __launch_bounds__(512)
void fused_mono(const float* __restrict__ x, const float* __restrict__ mask,
                const float* __restrict__ bproj, const float* __restrict__ BIAS,
                const bf16* __restrict__ WtQKV, const bf16* __restrict__ WtP,
                float* __restrict__ out)
{
  __shared__ __align__(16) char smem[M_LDS];
  bf16* O_lds  = (bf16*)(smem + M_OFF_O);
  bf16* q_lds  = (bf16*)(smem + M_OFF_Q);
  bf16* k_lds  = (bf16*)(smem + M_OFF_K);
  bf16* vT_lds = (bf16*)(smem + M_OFF_V);
  bf16* P_lds  = (bf16*)(smem + M_OFF_P);
  bf16* w_lds  = (bf16*)(smem + M_OFF_W);

  const int b    = blockIdx.x;
  const int tid  = threadIdx.x;
  const int wave = tid >> 6;
  const int lane = tid & 63;
  const int g    = lane >> 4;
  const int li   = lane & 15;
  const int wi   = b & 63;

  v8s afr[12];
  if (wave < 7) {
    int arow = 16 * wave + li; if (arow > 98) arow = 98;
    const float* xb = x + ((size_t)b * NTOK + arow) * CDIM + g * 8;
    #pragma unroll
    for (int s = 0; s < 12; ++s) {
      v4f x0 = *(const v4f*)(xb + s * 32);
      v4f x1 = *(const v4f*)(xb + s * 32 + 4);
      v8s f;
      #pragma unroll
      for (int j = 0; j < 4; ++j) { f[j] = f2bf(x0[j]); f[j + 4] = f2bf(x1[j]); }
      afr[s] = f;
    }
  }

  for (int h = 0; h < NHEAD; ++h) {
    v4f qacc[6];
    #pragma unroll
    for (int t = 0; t < 6; ++t) qacc[t] = (v4f){0.f, 0.f, 0.f, 0.f};
    #pragma unroll
    for (int c4 = 0; c4 < 4; ++c4) {
      for (int idx = tid; idx < 96 * 12; idx += 512) {
        int rr = idx / 12, ch = idx - rr * 12;
        int cg = (rr < 32) ? (h * 32 + rr)
               : (rr < 64) ? (CDIM + h * 32 + rr - 32)
                           : (2 * CDIM + h * 32 + rr - 64);
        *(v8s*)(w_lds + rr * WS_LD + ch * 8) =
            *(const v8s*)(WtQKV + (size_t)cg * CDIM + c4 * 96 + ch * 8);
      }
      __syncthreads();
      if (wave < 7) {
        #pragma unroll
        for (int ss = 0; ss < 3; ++ss) {
          const int s = c4 * 3 + ss;
          #pragma unroll
          for (int t = 0; t < 6; ++t) {
            v8s bw = *(const v8s*)(w_lds + (16 * t + li) * WS_LD + ss * 32 + g * 8);
            qacc[t] = mfma16x16x32(afr[s], bw, qacc[t]);
          }
        }
      }
      __syncthreads();
    }
    if (wave < 7) {
      #pragma unroll
      for (int t = 0; t < 6; ++t) {
        #pragma unroll
        for (int j = 0; j < 4; ++j) {
          int row = 16 * wave + g * 4 + j;
          int col = 16 * (t & 1) + li;
          float v = qacc[t][j];
          if (t < 2)      q_lds[row * QK_LD + col] = __float2bfloat16(v * SCALEF);
          else if (t < 4) k_lds[row * QK_LD + col] = __float2bfloat16(v);
          else            vT_lds[col * VT_LD + row] = __float2bfloat16(v);
        }
      }
    }
    vT_lds[(tid >> 4) * VT_LD + 112 + (tid & 15)] = __float2bfloat16(0.f);
    __syncthreads();

    if (wave < 7) {
      v8s aq = *(const v8s*)(q_lds + (16 * wave + li) * QK_LD + g * 8);
      v4f sacc[7];
      #pragma unroll
      for (int t = 0; t < 7; ++t) {
        v8s bk = *(const v8s*)(k_lds + (16 * t + li) * QK_LD + g * 8);
        v4f z = (v4f){0.f, 0.f, 0.f, 0.f};
        sacc[t] = mfma16x16x32(aq, bk, z);
      }
      #pragma unroll
      for (int t = 0; t < 7; ++t) {
        int col = 16 * t + li;
        #pragma unroll
        for (int j = 0; j < 4; ++j) {
          int row = 16 * wave + g * 4 + j;
          float s = sacc[t][j];
          if (col >= NTOK) s = -1e30f;
          else if (row < NTOK) {
            s += BIAS[(h * NTOK + row) * NTOK + col];
            if (row > 0 && col > 0)
              s += mask[((size_t)wi * 98 + (row - 1)) * 98 + (col - 1)];
          }
          sacc[t][j] = s;
        }
      }
      float linv[4];
      #pragma unroll
      for (int j = 0; j < 4; ++j) {
        float m = -1e30f;
        #pragma unroll
        for (int t = 0; t < 7; ++t) m = fmaxf(m, sacc[t][j]);
        m = fmaxf(m, __shfl_xor(m, 1));
        m = fmaxf(m, __shfl_xor(m, 2));
        m = fmaxf(m, __shfl_xor(m, 4));
        m = fmaxf(m, __shfl_xor(m, 8));
        float l = 0.f;
        #pragma unroll
        for (int t = 0; t < 7; ++t) {
          float p = __expf(sacc[t][j] - m);
          sacc[t][j] = p;
          l += p;
        }
        l += __shfl_xor(l, 1);
        l += __shfl_xor(l, 2);
        l += __shfl_xor(l, 4);
        l += __shfl_xor(l, 8);
        linv[j] = 1.f / l;
        int row = 16 * wave + g * 4 + j;
        #pragma unroll
        for (int t = 0; t < 7; ++t)
          P_lds[row * P_LD + 16 * t + li] = __float2bfloat16(sacc[t][j]);
        P_lds[row * P_LD + 112 + li] = __float2bfloat16(0.f);
      }
      v4f oacc[2];
      oacc[0] = (v4f){0.f, 0.f, 0.f, 0.f};
      oacc[1] = (v4f){0.f, 0.f, 0.f, 0.f};
      #pragma unroll
      for (int ks = 0; ks < 4; ++ks) {
        v8s ap = *(const v8s*)(P_lds + (16 * wave + li) * P_LD + ks * 32 + g * 8);
        #pragma unroll
        for (int t = 0; t < 2; ++t) {
          v8s bv = *(const v8s*)(vT_lds + (16 * t + li) * VT_LD + ks * 32 + g * 8);
          oacc[t] = mfma16x16x32(ap, bv, oacc[t]);
        }
      }
      #pragma unroll
      for (int t = 0; t < 2; ++t) {
        #pragma unroll
        for (int j = 0; j < 4; ++j) {
          int row = 16 * wave + g * 4 + j;
          if (row < NTOK)
            O_lds[row * M_O_LD + h * 32 + 16 * t + li] =
                __float2bfloat16(oacc[t][j] * linv[j]);
        }
      }
    }
    __syncthreads();
  }

  const size_t OUT2 = (size_t)1024 * 98 * CDIM;
  const int orow_clamped = (16 * wave + li > 98) ? 98 : 16 * wave + li;
  for (int cc = 0; cc < 4; ++cc) {
    v4f pacc[6];
    #pragma unroll
    for (int t = 0; t < 6; ++t) pacc[t] = (v4f){0.f, 0.f, 0.f, 0.f};
    for (int c4 = 0; c4 < 4; ++c4) {
      for (int idx = tid; idx < 96 * 12; idx += 512) {
        int rr = idx / 12, ch = idx - rr * 12;
        *(v8s*)(w_lds + rr * WS_LD + ch * 8) =
            *(const v8s*)(WtP + ((size_t)(cc * 96 + rr)) * CDIM + c4 * 96 + ch * 8);
      }
      __syncthreads();
      if (wave < 7) {
        #pragma unroll
        for (int ss = 0; ss < 3; ++ss) {
          const int s = c4 * 3 + ss;
          v8s ao = *(const v8s*)(O_lds + orow_clamped * M_O_LD + s * 32 + g * 8);
          #pragma unroll
          for (int t = 0; t < 6; ++t) {
            v8s bw = *(const v8s*)(w_lds + (16 * t + li) * WS_LD + ss * 32 + g * 8);
            pacc[t] = mfma16x16x32(ao, bw, pacc[t]);
          }
        }
      }
      __syncthreads();
    }
    if (wave < 7) {
      #pragma unroll
      for (int t = 0; t < 6; ++t) {
        #pragma unroll
        for (int j = 0; j < 4; ++j) {
          int row = 16 * wave + g * 4 + j;
          if (row < NTOK) {
            int col = cc * 96 + 16 * t + li;
            float v = pacc[t][j] + bproj[col];
            if (row == 0) out[OUT2 + (size_t)b * CDIM + col] = v;
            else          out[((size_t)b * 98 + (row - 1)) * CDIM + col] = v;
          }
        }
      }
    }
  }
}

extern "C" void kernel_launch(void* const* d_in, const int* in_sizes, int n_in,
                              void* d_out, int out_size, void* d_ws, size_t ws_size,
                              hipStream_t stream) {
  const float* x     = (const float*)d_in[0];
  const float* mask  = (const float*)d_in[1];
  const float* Wqkv  = (const float*)d_in[2];
  const float* rpb   = (const float*)d_in[3];
  const float* Wproj = (const float*)d_in[4];
  const float* bproj = (const float*)d_in[5];
  const int*   rpi   = (const int*)d_in[6];

  bf16*  WtQKV = (bf16*)((char*)d_ws + WT_QKV_OFF);
  bf16*  WtP   = (bf16*)((char*)d_ws + WT_P_OFF);
  float* BIAS  = (float*)((char*)d_ws + BIAS_OFF);
  bf16*  BMF   = (bf16*)((char*)d_ws + BMF_OFF);

  const bool full = (ws_size >= WS_FULL);
  const int prep_items = full ? PREP_W : PREP_BASE;   // BIAS only for MID/MONO
  prep_kernel<<<(prep_items + 255) / 256, 256, 0, stream>>>(
      Wqkv, Wproj, rpb, rpi, WtQKV, WtP, BIAS, full ? 0 : 1);

  if (full) {
    bf16* qkv2 = (bf16*)((char*)d_ws + QKV_OFF);
    k_qkv<<<BMF_BLKS + 792 * 6, 512, 0, stream>>>(x, WtQKV, qkv2,
                                                  rpb, rpi, mask, BMF);
    k_attn<<<1024, 448, 0, stream>>>(BMF, qkv2);
    k2_proj2<<<792 * 2, 512, 0, stream>>>(qkv2, WtP, bproj, (float*)d_out);
  } else if (ws_size >= WS_MID) {
    bf16* O_ws = (bf16*)((char*)d_ws + O_WS_OFF);
    k1_attn<<<1024, 512, 0, stream>>>(x, mask, BIAS, WtQKV, O_ws);
    k2_proj<<<792 * 2, 512, 0, stream>>>(O_ws, WtP, bproj, (float*)d_out);
  } else {
    fused_mono<<<1024, 512, 0, stream>>>(x, mask, bproj, BIAS, WtQKV, WtP,
                                         (float*)d_out);
  }
}

// Round 23
// 377.775 us; speedup vs baseline: 1.0369x; 1.0369x over previous
//
#include <hip/hip_runtime.h>
#include <hip/hip_bf16.h>
#include <cstddef>
#include <cstdint>

// WindowAttention3D for MI355X (gfx950). Inputs f32, output f32.
// FULL (ws>=~255MB): k_qkv2 counted-vmcnt dbuf GEMM reading f32 x DIRECTLY
//   (A reg-staged + swizzled ds_write inside the pipeline; no x-cast pass),
//   BMF generation fused as prefix blocks; k_attn 1 block/window with
//   head-ahead prefetch + lgkm-only barriers; k2_proj2 counted-vmcnt dbuf.
// MID (ws>=~80MB): k1_attn + k2_proj. MONO: round-4 monolith.
// r23 FINAL: round-19 configuration (best measured: 378.4us, reproduced
// 379.0 in r21). r16 (fat tile), r20 (T14 reorder), r22 (single-buf 3blk/CU)
// all regressed or were null — this is the proven local optimum.

using bf16 = __hip_bfloat16;
typedef short v8s __attribute__((ext_vector_type(8)));
typedef short v4s __attribute__((ext_vector_type(4)));
typedef float v4f __attribute__((ext_vector_type(4)));

static constexpr int    NTOK   = 99;
static constexpr int    CDIM   = 384;
static constexpr int    NHEAD  = 12;
static constexpr int    NROWS  = 101376;             // 1024*99
static constexpr size_t PLANE  = (size_t)NROWS * 32;
static constexpr float  SCALEF = 0.17677669529663687f;

__device__ __forceinline__ v4f mfma16x16x32(v8s a, v8s b, v4f c) {
  return __builtin_amdgcn_mfma_f32_16x16x32_bf16(a, b, c, 0, 0, 0);
}
__device__ __forceinline__ short f2bf(float f) {
  bf16 h = __float2bfloat16(f);
  return *reinterpret_cast<short*>(&h);
}
__device__ __forceinline__ float bf2f(short s) {
  bf16 h = *reinterpret_cast<bf16*>(&s);
  return __bfloat162float(h);
}

#if defined(__has_builtin)
#if __has_builtin(__builtin_amdgcn_global_load_lds)
#define HAS_GLL 1
#endif
#endif
#ifndef HAS_GLL
#define HAS_GLL 0
#endif

__device__ __forceinline__ void gload_lds16(const bf16* gsrc, bf16* ldst, int lane) {
#if HAS_GLL
  __builtin_amdgcn_global_load_lds(
      (const __attribute__((address_space(1))) void*)gsrc,
      (__attribute__((address_space(3))) void*)ldst, 16, 0, 0);
#else
  *(v8s*)(ldst + lane * 8) = *(const v8s*)gsrc;
#endif
}

// ---- ws layout ----
static constexpr size_t WT_QKV_OFF = 0;
static constexpr size_t WT_P_OFF   = 884736;
static constexpr size_t BIAS_OFF   = 884736 + 294912;
static constexpr size_t COMMON_END = 1650096;
static constexpr size_t O_WS_OFF   = COMMON_END;
static constexpr size_t WS_MID     = O_WS_OFF + (size_t)NROWS * 384 * 2;
static constexpr size_t BMF_OFF    = COMMON_END;
static constexpr size_t BMF_BYTES  = (size_t)64 * NHEAD * 7 * 7 * 64 * 4 * 2;
static constexpr size_t QKV_OFF    = BMF_OFF + BMF_BYTES;
static constexpr size_t WS_FULL    = QKV_OFF + (size_t)NROWS * 1152 * 2;   // ~254.5MB

static constexpr int PREP_W    = 1152 * 384 + 384 * 384;          // weights only
static constexpr int PREP_BASE = PREP_W + NHEAD * 99 * 99;        // + BIAS (MID)
static constexpr int PREP_BMF2 = 64 * 112 * 112;                  // 802,816
static constexpr int BMF_BLKS  = (PREP_BMF2 + 511) / 512;         // 1568 (div by 8)

// ---------------- BMF generation (fused into k_qkv2 prefix blocks) ----------
__device__ __forceinline__ void bmf_gen_item(int j2, const float* __restrict__ rpb,
                                             const int* __restrict__ rpi,
                                             const float* __restrict__ mask,
                                             bf16* __restrict__ BMF)
{
  int col = j2 % 112;
  int r2  = j2 / 112;
  int row = r2 % 112;
  int wi  = r2 / 112;
  int w = row >> 4, g = (row >> 2) & 3, jj = row & 3;
  int t = col >> 4, li = col & 15, lane = g * 16 + li;
  bool in = (row >= 1 && row <= 98 && col >= 1 && col <= 98);
  int tix = 0; float mval = 0.f;
  if (in) {
    tix  = rpi[(row - 1) * 98 + (col - 1)];
    mval = mask[((size_t)wi * 98 + (row - 1)) * 98 + (col - 1)];
  }
  size_t base = (((size_t)wi * NHEAD * 7 + w) * 7 + t) * 256 + lane * 4 + jj;
  #pragma unroll
  for (int h = 0; h < NHEAD; ++h) {
    float v;
    if (col > 98)  v = -1e30f;              // baked column mask
    else           v = in ? (rpb[tix * NHEAD + h] + mval) : 0.f;
    BMF[base + (size_t)h * 12544] = __float2bfloat16(v);   // 12544 = 49*256
  }
}

// ---------------- prep: weight transposes (+ BIAS for MID tier) -------------
__global__ void prep_kernel(const float* __restrict__ Wqkv, const float* __restrict__ Wproj,
                            const float* __restrict__ rpb,  const int* __restrict__ rpi,
                            bf16* __restrict__ WtQKV, bf16* __restrict__ WtP,
                            float* __restrict__ BIAS, int do_bias)
{
  int idx = blockIdx.x * 256 + threadIdx.x;
  if (idx < 1152 * 384) {
    int c = idx / 384, k = idx - c * 384;
    WtQKV[idx] = __float2bfloat16(Wqkv[k * 1152 + c]);
  } else if (idx < PREP_W) {
    int j = idx - 1152 * 384;
    int c = j / 384, k = j - c * 384;
    WtP[j] = __float2bfloat16(Wproj[k * 384 + c]);
  } else if (do_bias && idx < PREP_BASE) {
    int j = idx - PREP_W;
    int h = j / (99 * 99), r = j % (99 * 99);
    int nn = r / 99, mm = r % 99;
    float v = 0.f;
    if (nn > 0 && mm > 0) v = rpb[rpi[(nn - 1) * 98 + (mm - 1)] * NHEAD + h];
    BIAS[j] = v;
  }
}

// ================= k_qkv2: counted-vmcnt dbuf GEMM, f32 A, fused BMF =========
// B staged via gload_lds (3/thread); A staged from f32 x via reg loads issued
// BEFORE B (so vmcnt(3) = "A landed, B in flight"), cvt + swizzled ds_write.
static constexpr int Q2_BUF  = 40960;         // B 24,576 + A 16,384
static constexpr int Q2_AOFF = 24576;
static constexpr int CSTG1_LD = 200;          // single-pass epilogue stride

__global__ __launch_bounds__(512)
void k_qkv2(const float* __restrict__ x, const bf16* __restrict__ WtQKV,
            bf16* __restrict__ qkv2,
            const float* __restrict__ rpb, const int* __restrict__ rpi,
            const float* __restrict__ mask, bf16* __restrict__ BMF)
{
  __shared__ __align__(16) char smem[2 * Q2_BUF];   // 81,920 B -> 2 blocks/CU
  bf16* C_stg = (bf16*)(smem);                      // 128x200x2 = 51,200 B

  // ---- prefix blocks: BMF generation (overlaps with GEMM residency) ----
  if (blockIdx.x < BMF_BLKS) {
    int j2 = blockIdx.x * 512 + threadIdx.x;
    if (j2 < PREP_BMF2) bmf_gen_item(j2, rpb, rpi, mask, BMF);
    return;
  }
  const int bid  = blockIdx.x - BMF_BLKS;           // 0..4751

  const int tid  = threadIdx.x;
  const int wave = tid >> 6;
  const int wm   = wave >> 2;
  const int wn   = wave & 3;
  const int lane = tid & 63;
  const int g    = lane >> 4;
  const int li   = lane & 15;
  const int tile = (bid & 7) * 594 + (bid >> 3);    // 4752 = 8*594
  const int R0   = (tile / 6) * 128;
  const int CN   = (tile % 6) * 192;

  // A staging coords: thread (arr, ak8) handles rows arr, arr+64; global chunk
  // ak8. Swizzled LDS slot: lc = ak8 ^ (row&7)  (row&7 == arr&7; 64%8==0).
  const int arr = tid >> 3, ak8 = tid & 7;
  const int alc = ak8 ^ (arr & 7);

  v4f acc[4][3];
  #pragma unroll
  for (int mi = 0; mi < 4; ++mi)
    #pragma unroll
    for (int ni = 0; ni < 3; ++ni) acc[mi][ni] = (v4f){0.f, 0.f, 0.f, 0.f};

  v4f areg[2][2];
  auto loadA = [&](int kc) {                  // 4 vmem loads (issued FIRST)
    const int k0 = kc * 64;
    #pragma unroll
    for (int p = 0; p < 2; ++p) {
      const float* src = x + (size_t)(R0 + arr + p * 64) * 384 + k0 + ak8 * 8;
      areg[p][0] = *(const v4f*)(src);
      areg[p][1] = *(const v4f*)(src + 4);
    }
  };
  auto loadB = [&](int kc, int buf) {         // 3 gload_lds (issued LAST)
    const int k0 = kc * 64;
    bf16* Bl = (bf16*)(smem + buf * Q2_BUF);
    #pragma unroll
    for (int p = 0; p < 3; ++p) {
      int q = wave * 3 + p;
      int row = q * 8 + (lane >> 3);
      int c = (lane & 7) ^ (row & 7);
      gload_lds16(WtQKV + (size_t)(CN + row) * 384 + k0 + c * 8, Bl + q * 512, lane);
    }
  };
  auto writeA = [&](int buf) {                // cvt + swizzled ds_write
    bf16* Al = (bf16*)(smem + buf * Q2_BUF + Q2_AOFF);
    #pragma unroll
    for (int p = 0; p < 2; ++p) {
      v8s f;
      #pragma unroll
      for (int j = 0; j < 4; ++j) { f[j] = f2bf(areg[p][0][j]); f[j + 4] = f2bf(areg[p][1][j]); }
      *(v8s*)(Al + (arr + p * 64) * 64 + alc * 8) = f;
    }
  };

  // prologue: stage chunk 0 into buf 0
  loadA(0);
  loadB(0, 0);
  asm volatile("s_waitcnt vmcnt(3)" ::: "memory");  // A0 landed; B0 in flight
  writeA(0);

  for (int kc = 0; kc < 6; ++kc) {
    if (kc < 5) {
      loadA(kc + 1);                          // 4 reg loads (older)
      loadB(kc + 1, (kc + 1) & 1);            // 3 gloads (newest)
      asm volatile("s_waitcnt vmcnt(3)" ::: "memory");  // A(kc+1)+B(kc) landed
      writeA((kc + 1) & 1);                   // buf free since barrier2(kc-1)
      asm volatile("s_waitcnt lgkmcnt(0)" ::: "memory");
    } else {
      asm volatile("s_waitcnt vmcnt(0) lgkmcnt(0)" ::: "memory");
    }
    __builtin_amdgcn_s_barrier();
    __builtin_amdgcn_sched_barrier(0);
    const bf16* Bl = (const bf16*)(smem + (kc & 1) * Q2_BUF);
    const bf16* Al = (const bf16*)(smem + (kc & 1) * Q2_BUF + Q2_AOFF);
    #pragma unroll
    for (int ks = 0; ks < 2; ++ks) {
      v8s af[4], bfr[3];
      #pragma unroll
      for (int mi = 0; mi < 4; ++mi) {
        int arow2 = wm * 64 + mi * 16 + li;
        int sc    = (4 * ks + g) ^ (arow2 & 7);
        af[mi] = *(const v8s*)(Al + arow2 * 64 + sc * 8);
      }
      #pragma unroll
      for (int ni = 0; ni < 3; ++ni) {
        int brow = wn * 48 + ni * 16 + li;
        int sc   = (4 * ks + g) ^ (brow & 7);
        bfr[ni] = *(const v8s*)(Bl + brow * 64 + sc * 8);
      }
      #pragma unroll
      for (int mi = 0; mi < 4; ++mi)
        #pragma unroll
        for (int ni = 0; ni < 3; ++ni)
          acc[mi][ni] = mfma16x16x32(af[mi], bfr[ni], acc[mi][ni]);
    }
    __builtin_amdgcn_sched_barrier(0);
    __builtin_amdgcn_s_barrier();          // all reads of buf(kc) done
  }

  // ---- single-pass epilogue: acc -> C_stg -> coalesced plane stores ----
  const float scale = (CN < 384) ? SCALEF : 1.f;
  #pragma unroll
  for (int mi = 0; mi < 4; ++mi)
    #pragma unroll
    for (int ni = 0; ni < 3; ++ni)
      #pragma unroll
      for (int j = 0; j < 4; ++j)
        C_stg[(wm * 64 + mi * 16 + g * 4 + j) * CSTG1_LD + wn * 48 + ni * 16 + li] =
            __float2bfloat16(acc[mi][ni][j] * scale);
  __syncthreads();
  const int r_ep = tid >> 2, d8 = tid & 3;
  #pragma unroll
  for (int cidx = 0; cidx < 6; ++cidx) {
    int c_global = CN + cidx * 32;
    int seg = c_global / 384, hh = (c_global % 384) >> 5;
    bf16* plane = qkv2 + (size_t)(hh * 3 + seg) * PLANE;
    v8s val = *(const v8s*)(C_stg + r_ep * CSTG1_LD + cidx * 32 + d8 * 8);
    *(v8s*)(plane + (size_t)(R0 + r_ep) * 32 + d8 * 8) = val;
  }
}

// ================= k_attn v4: 12 heads/block, full head-ahead prefetch =======
static constexpr int A_VT_LD = 136;
static constexpr int A_P_LD  = 136;
static constexpr int A_OFF_V = 0;
static constexpr int A_OFF_P = A_OFF_V + 32 * A_VT_LD * 2;
static constexpr int A_LDS   = A_OFF_P + 112 * A_P_LD * 2;   // 39,168 B

__global__ __launch_bounds__(448)
void k_attn(const bf16* __restrict__ BMF, bf16* __restrict__ qkv2)
{
  __shared__ __align__(16) char smem[A_LDS];
  bf16* vT_lds = (bf16*)(smem + A_OFF_V);
  bf16* P_lds  = (bf16*)(smem + A_OFF_P);

  const int b    = blockIdx.x;
  const int tid  = threadIdx.x;
  const int wave = tid >> 6;
  const int lane = tid & 63;
  const int g    = lane >> 4;
  const int li   = lane & 15;
  const int wi   = b & 63;

  const int r = tid >> 2, l4 = tid & 3;
  const size_t voff = ((size_t)b * NTOK + ((r > 98) ? 98 : r)) * 32 + l4 * 8;

  const int qrow = (16 * wave + li > 98) ? 98 : 16 * wave + li;
  const size_t qoff = ((size_t)b * NTOK + qrow) * 32 + g * 8;
  int koff[7];
  #pragma unroll
  for (int t = 0; t < 7; ++t) {
    int krow = 16 * t + li; if (krow > 98) krow = 98;
    koff[t] = (b * NTOK + krow) * 32 + g * 8;
  }
  const bf16* bmw = BMF + ((size_t)(wi * NHEAD) * 7 + wave) * 7 * 256 + lane * 4;

  // V(h0) load in flight while we zero LDS
  v8s pv = *(const v8s*)(qkv2 + (size_t)2 * PLANE + voff);

  for (int z = tid; z < A_LDS / 16; z += 448)
    *(v8s*)(smem + z * 16) = (v8s){0, 0, 0, 0, 0, 0, 0, 0};
  __syncthreads();

  if (r < NTOK) {
    #pragma unroll
    for (int e = 0; e < 8; ++e)
      *(short*)(vT_lds + (l4 * 8 + e) * A_VT_LD + r) = pv[e];
  }

  // first head's K/Q fragments + BMF tile
  v8s kf[7], qf;
  v4s bmr[7];
  {
    const bf16* kp = qkv2 + (size_t)1 * PLANE;
    #pragma unroll
    for (int t = 0; t < 7; ++t) kf[t] = *(const v8s*)(kp + koff[t]);
    qf = *(const v8s*)(qkv2 + qoff);
    #pragma unroll
    for (int t = 0; t < 7; ++t)
      bmr[t] = *(const v4s*)(bmw + t * 256);
  }
  __syncthreads();

  for (int h = 0; h < NHEAD; ++h) {
    // S = q k^T (consumes kf/qf before prefetch overwrites)
    v4f sacc[7];
    #pragma unroll
    for (int t = 0; t < 7; ++t) {
      v4f z = (v4f){0.f, 0.f, 0.f, 0.f};
      sacc[t] = mfma16x16x32(qf, kf[t], z);
    }

    // prefetch next head's K/Q/V (fly during softmax + PV)
    v8s nv;
    if (h < NHEAD - 1) {
      const bf16* kp = qkv2 + (size_t)((h + 1) * 3 + 1) * PLANE;
      #pragma unroll
      for (int t = 0; t < 7; ++t) kf[t] = *(const v8s*)(kp + koff[t]);
      qf = *(const v8s*)(qkv2 + (size_t)((h + 1) * 3) * PLANE + qoff);
      nv = *(const v8s*)(qkv2 + (size_t)((h + 1) * 3 + 2) * PLANE + voff);
    }

    // bias + mask, unconditional (pad cols carry -1e30); consumes bmr(h)
    #pragma unroll
    for (int t = 0; t < 7; ++t)
      #pragma unroll
      for (int j = 0; j < 4; ++j)
        sacc[t][j] += bf2f(bmr[t][j]);

    // prefetch next head's BMF tile
    if (h < NHEAD - 1) {
      const bf16* bmb = bmw + (size_t)(h + 1) * 12544;
      #pragma unroll
      for (int t = 0; t < 7; ++t)
        bmr[t] = *(const v4s*)(bmb + t * 256);
    }

    // softmax (rows live in 16-lane groups)
    float linv[4];
    #pragma unroll
    for (int j = 0; j < 4; ++j) {
      float m = -1e30f;
      #pragma unroll
      for (int t = 0; t < 7; ++t) m = fmaxf(m, sacc[t][j]);
      m = fmaxf(m, __shfl_xor(m, 1));
      m = fmaxf(m, __shfl_xor(m, 2));
      m = fmaxf(m, __shfl_xor(m, 4));
      m = fmaxf(m, __shfl_xor(m, 8));
      float l = 0.f;
      #pragma unroll
      for (int t = 0; t < 7; ++t) {
        float p = __expf(sacc[t][j] - m);
        sacc[t][j] = p;
        l += p;
      }
      l += __shfl_xor(l, 1);
      l += __shfl_xor(l, 2);
      l += __shfl_xor(l, 4);
      l += __shfl_xor(l, 8);
      linv[j] = 1.f / l;
      int row = 16 * wave + g * 4 + j;
      #pragma unroll
      for (int t = 0; t < 7; ++t)
        P_lds[row * A_P_LD + 16 * t + li] = __float2bfloat16(sacc[t][j]);
    }
    // PV: pure MFMA over padded k=0..127
    v4f oacc[2];
    oacc[0] = (v4f){0.f, 0.f, 0.f, 0.f};
    oacc[1] = (v4f){0.f, 0.f, 0.f, 0.f};
    #pragma unroll
    for (int ks = 0; ks < 4; ++ks) {
      v8s ap = *(const v8s*)(P_lds + (16 * wave + li) * A_P_LD + ks * 32 + g * 8);
      #pragma unroll
      for (int t = 0; t < 2; ++t) {
        v8s bv = *(const v8s*)(vT_lds + (16 * t + li) * A_VT_LD + ks * 32 + g * 8);
        oacc[t] = mfma16x16x32(ap, bv, oacc[t]);
      }
    }
    // O -> dead q-plane of head h (stores NOT drained at barriers below)
    bf16* oplane = qkv2 + (size_t)(h * 3) * PLANE;
    #pragma unroll
    for (int t = 0; t < 2; ++t)
      #pragma unroll
      for (int j = 0; j < 4; ++j) {
        int row = 16 * wave + g * 4 + j;
        if (row < NTOK)
          oplane[((size_t)b * NTOK + row) * 32 + 16 * t + li] =
              __float2bfloat16(oacc[t][j] * linv[j]);
      }

    // LDS-only barrier: all waves' ds_reads of vT(h)/P(h) complete
    asm volatile("s_waitcnt lgkmcnt(0)" ::: "memory");
    asm volatile("s_barrier" ::: "memory");
    if (h < NHEAD - 1) {
      if (r < NTOK) {
        #pragma unroll
        for (int e = 0; e < 8; ++e)
          *(short*)(vT_lds + (l4 * 8 + e) * A_VT_LD + r) = nv[e];
      }
      asm volatile("s_waitcnt lgkmcnt(0)" ::: "memory");
      asm volatile("s_barrier" ::: "memory");
    }
  }
}

// ================= k2_proj2: counted-vmcnt dbuf proj (FULL tier) =============
__global__ __launch_bounds__(512)
void k2_proj2(const bf16* __restrict__ O_src, const bf16* __restrict__ WtP,
              const float* __restrict__ bproj, float* __restrict__ out)
{
  __shared__ __align__(16) char smem[2 * Q2_BUF];

  const int tid  = threadIdx.x;
  const int wave = tid >> 6;
  const int wm   = wave >> 2;
  const int wn   = wave & 3;
  const int lane = tid & 63;
  const int g    = lane >> 4;
  const int li   = lane & 15;
  const int tile = (blockIdx.x & 7) * 198 + (blockIdx.x >> 3);
  const int R0   = (tile >> 1) * 128;
  const int CN   = (tile & 1) * 192;

  v4f acc[4][3];
  #pragma unroll
  for (int mi = 0; mi < 4; ++mi)
    #pragma unroll
    for (int ni = 0; ni < 3; ++ni) acc[mi][ni] = (v4f){0.f, 0.f, 0.f, 0.f};

  auto stage = [&](int kc, int buf) {
    const int k0 = kc * 64;
    bf16* Wl = (bf16*)(smem + buf * Q2_BUF);
    bf16* Ol = (bf16*)(smem + buf * Q2_BUF + Q2_AOFF);
    #pragma unroll
    for (int p = 0; p < 3; ++p) {
      int q = wave * 3 + p;
      int row = q * 8 + (lane >> 3);
      int c = (lane & 7) ^ (row & 7);
      gload_lds16(WtP + (size_t)(CN + row) * CDIM + k0 + c * 8, Wl + q * 512, lane);
    }
    #pragma unroll
    for (int p = 0; p < 2; ++p) {
      int q = wave * 2 + p;
      int row = q * 8 + (lane >> 3);
      int c = (lane & 7) ^ (row & 7);
      int kk = k0 + c * 8, hh = kk >> 5, d = kk & 31;
      gload_lds16(O_src + (size_t)(hh * 3) * PLANE + (size_t)(R0 + row) * 32 + d,
                  Ol + q * 512, lane);
    }
  };

  stage(0, 0);
  for (int kc = 0; kc < 6; ++kc) {
    if (kc < 5) {
      stage(kc + 1, (kc + 1) & 1);
      asm volatile("s_waitcnt vmcnt(5)" ::: "memory");
    } else {
      asm volatile("s_waitcnt vmcnt(0)" ::: "memory");
    }
    __builtin_amdgcn_s_barrier();
    __builtin_amdgcn_sched_barrier(0);
    const bf16* Wl = (const bf16*)(smem + (kc & 1) * Q2_BUF);
    const bf16* Ol = (const bf16*)(smem + (kc & 1) * Q2_BUF + Q2_AOFF);
    #pragma unroll
    for (int ks = 0; ks < 2; ++ks) {
      v8s af[4], bfr[3];
      #pragma unroll
      for (int mi = 0; mi < 4; ++mi) {
        int arow = wm * 64 + mi * 16 + li;
        int sc   = (4 * ks + g) ^ (arow & 7);
        af[mi] = *(const v8s*)(Ol + arow * 64 + sc * 8);
      }
      #pragma unroll
      for (int ni = 0; ni < 3; ++ni) {
        int brow = wn * 48 + ni * 16 + li;
        int sc   = (4 * ks + g) ^ (brow & 7);
        bfr[ni] = *(const v8s*)(Wl + brow * 64 + sc * 8);
      }
      #pragma unroll
      for (int mi = 0; mi < 4; ++mi)
        #pragma unroll
        for (int ni = 0; ni < 3; ++ni)
          acc[mi][ni] = mfma16x16x32(af[mi], bfr[ni], acc[mi][ni]);
    }
    __builtin_amdgcn_sched_barrier(0);
    __builtin_amdgcn_s_barrier();
  }

  const size_t OUT2 = (size_t)1024 * 98 * CDIM;
  #pragma unroll
  for (int mi = 0; mi < 4; ++mi)
    #pragma unroll
    for (int ni = 0; ni < 3; ++ni) {
      int col = CN + wn * 48 + ni * 16 + li;
      float bb = bproj[col];
      #pragma unroll
      for (int j = 0; j < 4; ++j) {
        int rr = R0 + wm * 64 + mi * 16 + g * 4 + j;
        int b = rr / 99, n = rr - b * 99;
        float v = acc[mi][ni][j] + bb;
        if (n == 0) out[OUT2 + (size_t)b * CDIM + col] = v;
        else        out[((size_t)b * 98 + (n - 1)) * CDIM + col] = v;
      }
    }
}

// ================= k2_proj: MID-tier linear-O version ========================
static constexpr int K2_LD   = 72;
static constexpr int K2_OFFW = 0;
static constexpr int K2_OFFO = 192 * K2_LD * 2;
static constexpr int K2_LDS  = K2_OFFO + 128 * K2_LD * 2;

__global__ __launch_bounds__(512)
void k2_proj(const bf16* __restrict__ O_src, const bf16* __restrict__ WtP,
             const float* __restrict__ bproj, float* __restrict__ out)
{
  __shared__ __align__(16) char smem[K2_LDS];
  bf16* W_lds = (bf16*)(smem + K2_OFFW);
  bf16* O_lds = (bf16*)(smem + K2_OFFO);

  const int tid  = threadIdx.x;
  const int wave = tid >> 6;
  const int wm   = wave >> 2;
  const int wn   = wave & 3;
  const int lane = tid & 63;
  const int g    = lane >> 4;
  const int li   = lane & 15;
  const int tile = (blockIdx.x & 7) * 198 + (blockIdx.x >> 3);
  const int R0   = (tile >> 1) * 128;
  const int CN   = (tile & 1) * 192;

  v4f acc[4][3];
  #pragma unroll
  for (int mi = 0; mi < 4; ++mi)
    #pragma unroll
    for (int ni = 0; ni < 3; ++ni) acc[mi][ni] = (v4f){0.f, 0.f, 0.f, 0.f};

  for (int kc = 0; kc < 6; ++kc) {
    const int k0 = kc * 64;
    #pragma unroll
    for (int p = 0; p < 3; ++p) {
      int it = tid + p * 512, rr = it >> 3, k8 = it & 7;
      *(v8s*)(W_lds + rr * K2_LD + k8 * 8) =
          *(const v8s*)(WtP + (size_t)(CN + rr) * CDIM + k0 + k8 * 8);
    }
    #pragma unroll
    for (int p = 0; p < 2; ++p) {
      int it = tid + p * 512, rr = it >> 3, k8 = it & 7;
      *(v8s*)(O_lds + rr * K2_LD + k8 * 8) =
          *(const v8s*)(O_src + (size_t)(R0 + rr) * 384 + k0 + k8 * 8);
    }
    __syncthreads();
    #pragma unroll
    for (int ks = 0; ks < 2; ++ks) {
      v8s af[4], bfr[3];
      #pragma unroll
      for (int mi = 0; mi < 4; ++mi)
        af[mi] = *(const v8s*)(O_lds + (wm * 64 + mi * 16 + li) * K2_LD + ks * 32 + g * 8);
      #pragma unroll
      for (int ni = 0; ni < 3; ++ni)
        bfr[ni] = *(const v8s*)(W_lds + (wn * 48 + ni * 16 + li) * K2_LD + ks * 32 + g * 8);
      #pragma unroll
      for (int mi = 0; mi < 4; ++mi)
        #pragma unroll
        for (int ni = 0; ni < 3; ++ni)
          acc[mi][ni] = mfma16x16x32(af[mi], bfr[ni], acc[mi][ni]);
    }
    __syncthreads();
  }

  const size_t OUT2 = (size_t)1024 * 98 * CDIM;
  #pragma unroll
  for (int mi = 0; mi < 4; ++mi)
    #pragma unroll
    for (int ni = 0; ni < 3; ++ni) {
      int col = CN + wn * 48 + ni * 16 + li;
      float bb = bproj[col];
      #pragma unroll
      for (int j = 0; j < 4; ++j) {
        int rr = R0 + wm * 64 + mi * 16 + g * 4 + j;
        int b = rr / 99, n = rr - b * 99;
        float v = acc[mi][ni][j] + bb;
        if (n == 0) out[OUT2 + (size_t)b * CDIM + col] = v;
        else        out[((size_t)b * 98 + (n - 1)) * CDIM + col] = v;
      }
    }
}

// ================= MID tier: round-5 proven k1_attn =========================
static constexpr int QK_LD = 40;
static constexpr int VT_LD = 136;
static constexpr int P_LD  = 136;
static constexpr int WS_LD = 104;
static constexpr int K1_OFF_Q = 0;
static constexpr int K1_OFF_K = K1_OFF_Q + 112 * QK_LD * 2;
static constexpr int K1_OFF_V = K1_OFF_K + 112 * QK_LD * 2;
static constexpr int K1_OFF_P = K1_OFF_V + 32  * VT_LD * 2;
static constexpr int K1_OFF_W = K1_OFF_P + 112 * P_LD  * 2;
static constexpr int K1_LDS   = K1_OFF_W + 96 * WS_LD * 2;

__global__ __launch_bounds__(512)
void k1_attn(const float* __restrict__ x, const float* __restrict__ mask,
             const float* __restrict__ BIAS, const bf16* __restrict__ WtQKV,
             bf16* __restrict__ O_ws)
{
  __shared__ __align__(16) char smem[K1_LDS];
  bf16* q_lds  = (bf16*)(smem + K1_OFF_Q);
  bf16* k_lds  = (bf16*)(smem + K1_OFF_K);
  bf16* vT_lds = (bf16*)(smem + K1_OFF_V);
  bf16* P_lds  = (bf16*)(smem + K1_OFF_P);
  bf16* w_lds  = (bf16*)(smem + K1_OFF_W);

  const int b    = blockIdx.x;
  const int tid  = threadIdx.x;
  const int wave = tid >> 6;
  const int lane = tid & 63;
  const int g    = lane >> 4;
  const int li   = lane & 15;
  const int wi   = b & 63;

  v8s afr[12];
  if (wave < 7) {
    int arow = 16 * wave + li; if (arow > 98) arow = 98;
    const float* xb = x + ((size_t)b * NTOK + arow) * CDIM + g * 8;
    #pragma unroll
    for (int s = 0; s < 12; ++s) {
      v4f x0 = *(const v4f*)(xb + s * 32);
      v4f x1 = *(const v4f*)(xb + s * 32 + 4);
      v8s f;
      #pragma unroll
      for (int j = 0; j < 4; ++j) { f[j] = f2bf(x0[j]); f[j + 4] = f2bf(x1[j]); }
      afr[s] = f;
    }
  }

  for (int h = 0; h < NHEAD; ++h) {
    v4f qacc[6];
    #pragma unroll
    for (int t = 0; t < 6; ++t) qacc[t] = (v4f){0.f, 0.f, 0.f, 0.f};
    #pragma unroll
    for (int c4 = 0; c4 < 4; ++c4) {
      for (int idx = tid; idx < 96 * 12; idx += 512) {
        int rr = idx / 12, ch = idx - rr * 12;
        int cg = (rr < 32) ? (h * 32 + rr)
               : (rr < 64) ? (CDIM + h * 32 + rr - 32)
                           : (2 * CDIM + h * 32 + rr - 64);
        *(v8s*)(w_lds + rr * WS_LD + ch * 8) =
            *(const v8s*)(WtQKV + (size_t)cg * CDIM + c4 * 96 + ch * 8);
      }
      __syncthreads();
      if (wave < 7) {
        #pragma unroll
        for (int ss = 0; ss < 3; ++ss) {
          const int s = c4 * 3 + ss;
          #pragma unroll
          for (int t = 0; t < 6; ++t) {
            v8s bw = *(const v8s*)(w_lds + (16 * t + li) * WS_LD + ss * 32 + g * 8);
            qacc[t] = mfma16x16x32(afr[s], bw, qacc[t]);
          }
        }
      }
      __syncthreads();
    }
    if (wave < 7) {
      #pragma unroll
      for (int t = 0; t < 6; ++t) {
        #pragma unroll
        for (int j = 0; j < 4; ++j) {
          int row = 16 * wave + g * 4 + j;
          int col = 16 * (t & 1) + li;
          float v = qacc[t][j];
          if (t < 2)      q_lds[row * QK_LD + col] = __float2bfloat16(v * SCALEF);
          else if (t < 4) k_lds[row * QK_LD + col] = __float2bfloat16(v);
          else            vT_lds[col * VT_LD + row] = __float2bfloat16(v);
        }
      }
    }
    vT_lds[(tid >> 4) * VT_LD + 112 + (tid & 15)] = __float2bfloat16(0.f);
    __syncthreads();

    if (wave < 7) {
      v8s aq = *(const v8s*)(q_lds + (16 * wave + li) * QK_LD + g * 8);
      v4f sacc[7];
      #pragma unroll
      for (int t = 0; t < 7; ++t) {
        v8s bk = *(const v8s*)(k_lds + (16 * t + li) * QK_LD + g * 8);
        v4f z = (v4f){0.f, 0.f, 0.f, 0.f};
        sacc[t] = mfma16x16x32(aq, bk, z);
      }
      #pragma unroll
      for (int t = 0; t < 7; ++t) {
        int col = 16 * t + li;
        #pragma unroll
        for (int j = 0; j < 4; ++j) {
          int row = 16 * wave + g * 4 + j;
          float s = sacc[t][j];
          if (col >= NTOK) s = -1e30f;
          else if (row < NTOK) {
            s += BIAS[(h * NTOK + row) * NTOK + col];
            if (row > 0 && col > 0)
              s += mask[((size_t)wi * 98 + (row - 1)) * 98 + (col - 1)];
          }
          sacc[t][j] = s;
        }
      }
      float linv[4];
      #pragma unroll
      for (int j = 0; j < 4; ++j) {
        float m = -1e30f;
        #pragma unroll
        for (int t = 0; t < 7; ++t) m = fmaxf(m, sacc[t][j]);
        m = fmaxf(m, __shfl_xor(m, 1));
        m = fmaxf(m, __shfl_xor(m, 2));
        m = fmaxf(m, __shfl_xor(m, 4));
        m = fmaxf(m, __shfl_xor(m, 8));
        float l = 0.f;
        #pragma unroll
        for (int t = 0; t < 7; ++t) {
          float p = __expf(sacc[t][j] - m);
          sacc[t][j] = p;
          l += p;
        }
        l += __shfl_xor(l, 1);
        l += __shfl_xor(l, 2);
        l += __shfl_xor(l, 4);
        l += __shfl_xor(l, 8);
        linv[j] = 1.f / l;
        int row = 16 * wave + g * 4 + j;
        #pragma unroll
        for (int t = 0; t < 7; ++t)
          P_lds[row * P_LD + 16 * t + li] = __float2bfloat16(sacc[t][j]);
        P_lds[row * P_LD + 112 + li] = __float2bfloat16(0.f);
      }
      v4f oacc[2];
      oacc[0] = (v4f){0.f, 0.f, 0.f, 0.f};
      oacc[1] = (v4f){0.f, 0.f, 0.f, 0.f};
      #pragma unroll
      for (int ks = 0; ks < 4; ++ks) {
        v8s ap = *(const v8s*)(P_lds + (16 * wave + li) * P_LD + ks * 32 + g * 8);
        #pragma unroll
        for (int t = 0; t < 2; ++t) {
          v8s bv = *(const v8s*)(vT_lds + (16 * t + li) * VT_LD + ks * 32 + g * 8);
          oacc[t] = mfma16x16x32(ap, bv, oacc[t]);
        }
      }
      #pragma unroll
      for (int t = 0; t < 2; ++t) {
        #pragma unroll
        for (int j = 0; j < 4; ++j) {
          int row = 16 * wave + g * 4 + j;
          if (row < NTOK)
            O_ws[((size_t)b * 99 + row) * CDIM + h * 32 + 16 * t + li] =
                __float2bfloat16(oacc[t][j] * linv[j]);
        }
      }
    }
    __syncthreads();
  }
}

// ================= MONO tier: round-4 proven =================================
static constexpr int M_O_LD = 392;
static constexpr int M_OFF_O = 0;
static constexpr int M_OFF_Q = M_OFF_O + 99  * M_O_LD * 2;
static constexpr int M_OFF_K = M_OFF_Q + 112 * QK_LD * 2;
static constexpr int M_OFF_V = M_OFF_K + 112 * QK_LD * 2;
static constexpr int M_OFF_P = M_OFF_V + 32  * VT_LD * 2;
static constexpr int M_OFF_W = M_OFF_P + 112 * P_LD  * 2;
static constexpr int M_LDS   = M_OFF_W + 96 * WS_LD * 2;

__global__ __launch_bounds__(512)
void fused_mono(const float* __restrict__ x, const float* __restrict__ mask,
                const float* __restrict__ bproj, const float* __restrict__ BIAS,
                const bf16* __restrict__ WtQKV, const bf16* __restrict__ WtP,
                float* __restrict__ out)
{
  __shared__ __align__(16) char smem[M_LDS];
  bf16* O_lds  = (bf16*)(smem + M_OFF_O);
  bf16* q_lds  = (bf16*)(smem + M_OFF_Q);
  bf16* k_lds  = (bf16*)(smem + M_OFF_K);
  bf16* vT_lds = (bf16*)(smem + M_OFF_V);
  bf16* P_lds  = (bf16*)(smem + M_OFF_P);
  bf16* w_lds  = (bf16*)(smem + M_OFF_W);

  const int b    = blockIdx.x;
  const int tid  = threadIdx.x;
  const int wave = tid >> 6;
  const int lane = tid & 63;
  const int g    = lane >> 4;
  const int li   = lane & 15;
  const int wi   = b & 63;

  v8s afr[12];
  if (wave < 7) {
    int arow = 16 * wave + li; if (arow > 98) arow = 98;
    const float* xb = x + ((size_t)b * NTOK + arow) * CDIM + g * 8;
    #pragma unroll
    for (int s = 0; s < 12; ++s) {
      v4f x0 = *(const v4f*)(xb + s * 32);
      v4f x1 = *(const v4f*)(xb + s * 32 + 4);
      v8s f;
      #pragma unroll
      for (int j = 0; j < 4; ++j) { f[j] = f2bf(x0[j]); f[j + 4] = f2bf(x1[j]); }
      afr[s] = f;
    }
  }

  for (int h = 0; h < NHEAD; ++h) {
    v4f qacc[6];
    #pragma unroll
    for (int t = 0; t < 6; ++t) qacc[t] = (v4f){0.f, 0.f, 0.f, 0.f};
    #pragma unroll
    for (int c4 = 0; c4 < 4; ++c4) {
      for (int idx = tid; idx < 96 * 12; idx += 512) {
        int rr = idx / 12, ch = idx - rr * 12;
        int cg = (rr < 32) ? (h * 32 + rr)
               : (rr < 64) ? (CDIM + h * 32 + rr - 32)
                           : (2 * CDIM + h * 32 + rr - 64);
        *(v8s*)(w_lds + rr * WS_LD + ch * 8) =
            *(const v8s*)(WtQKV + (size_t)cg * CDIM + c4 * 96 + ch * 8);
      }
      __syncthreads();
      if (wave < 7) {
        #pragma unroll
        for (int ss = 0; ss < 3; ++ss) {
          const int s = c4 * 3 + ss;
          #pragma unroll
          for (int t = 0; t < 6; ++t) {
            v8s bw = *(const v8s*)(w_lds + (16 * t + li) * WS_LD + ss * 32 + g * 8);
            qacc[t] = mfma16x16x32(afr[s], bw, qacc[t]);
          }
        }
      }
      __syncthreads();
    }
    if (wave < 7) {
      #pragma unroll
      for (int t = 0; t < 6; ++t) {
        #pragma unroll
        for (int j = 0; j < 4; ++j) {
          int row = 16 * wave + g * 4 + j;
          int col = 16 * (t & 1) + li;
          float v = qacc[t][j];
          if (t < 2)      q_lds[row * QK_LD + col] = __float2bfloat16(v * SCALEF);
          else if (t < 4) k_lds[row * QK_LD + col] = __float2bfloat16(v);
          else            vT_lds[col * VT_LD + row] = __float2bfloat16(v);
        }
      }
    }
    vT_lds[(tid >> 4) * VT_LD + 112 + (tid & 15)] = __float2bfloat16(0.f);
    __syncthreads();

    if (wave < 7) {
      v8s aq = *(const v8s*)(q_lds + (16 * wave + li) * QK_LD + g * 8);
      v4f sacc[7];
      #pragma unroll
      for (int t = 0; t < 7; ++t) {
        v8s bk = *(const v8s*)(k_lds + (16 * t + li) * QK_LD + g * 8);
        v4f z = (v4f){0.f, 0.f, 0.f, 0.f};
        sacc[t] = mfma16x16x32(aq, bk, z);
      }
      #pragma unroll
      for (int t = 0; t < 7; ++t) {
        int col = 16 * t + li;
        #pragma unroll
        for (int j = 0; j < 4; ++j) {
          int row = 16 * wave + g * 4 + j;
          float s = sacc[t][j];
          if (col >= NTOK) s = -1e30f;
          else if (row < NTOK) {
            s += BIAS[(h * NTOK + row) * NTOK + col];
            if (row > 0 && col > 0)
              s += mask[((size_t)wi * 98 + (row - 1)) * 98 + (col - 1)];
          }
          sacc[t][j] = s;
        }
      }
      float linv[4];
      #pragma unroll
      for (int j = 0; j < 4; ++j) {
        float m = -1e30f;
        #pragma unroll
        for (int t = 0; t < 7; ++t) m = fmaxf(m, sacc[t][j]);
        m = fmaxf(m, __shfl_xor(m, 1));
        m = fmaxf(m, __shfl_xor(m, 2));
        m = fmaxf(m, __shfl_xor(m, 4));
        m = fmaxf(m, __shfl_xor(m, 8));
        float l = 0.f;
        #pragma unroll
        for (int t = 0; t < 7; ++t) {
          float p = __expf(sacc[t][j] - m);
          sacc[t][j] = p;
          l += p;
        }
        l += __shfl_xor(l, 1);
        l += __shfl_xor(l, 2);
        l += __shfl_xor(l, 4);
        l += __shfl_xor(l, 8);
        linv[j] = 1.f / l;
        int row = 16 * wave + g * 4 + j;
        #pragma unroll
        for (int t = 0; t < 7; ++t)
          P_lds[row * P_LD + 16 * t + li] = __float2bfloat16(sacc[t][j]);
        P_lds[row * P_LD + 112 + li] = __float2bfloat16(0.f);
      }
      v4f oacc[2];
      oacc[0] = (v4f){0.f, 0.f, 0.f, 0.f};
      oacc[1] = (v4f){0.f, 0.f, 0.f, 0.f};
      #pragma unroll
      for (int ks = 0; ks < 4; ++ks) {
        v8s ap = *(const v8s*)(P_lds + (16 * wave + li) * P_LD + ks * 32 + g * 8);
        #pragma unroll
        for (int t = 0; t < 2; ++t) {
          v8s bv = *(const v8s*)(vT_lds + (16 * t + li) * VT_LD + ks * 32 + g * 8);
          oacc[t] = mfma16x16x32(ap, bv, oacc[t]);
        }
      }
      #pragma unroll
      for (int t = 0; t < 2; ++t) {
        #pragma unroll
        for (int j = 0; j < 4; ++j) {
          int row = 16 * wave + g * 4 + j;
          if (row < NTOK)
            O_lds[row * M_O_LD + h * 32 + 16 * t + li] =
                __float2bfloat16(oacc[t][j] * linv[j]);
        }
      }
    }
    __syncthreads();
  }

  const size_t OUT2 = (size_t)1024 * 98 * CDIM;
  const int orow_clamped = (16 * wave + li > 98) ? 98 : 16 * wave + li;
  for (int cc = 0; cc < 4; ++cc) {
    v4f pacc[6];
    #pragma unroll
    for (int t = 0; t < 6; ++t) pacc[t] = (v4f){0.f, 0.f, 0.f, 0.f};
    for (int c4 = 0; c4 < 4; ++c4) {
      for (int idx = tid; idx < 96 * 12; idx += 512) {
        int rr = idx / 12, ch = idx - rr * 12;
        *(v8s*)(w_lds + rr * WS_LD + ch * 8) =
            *(const v8s*)(WtP + ((size_t)(cc * 96 + rr)) * CDIM + c4 * 96 + ch * 8);
      }
      __syncthreads();
      if (wave < 7) {
        #pragma unroll
        for (int ss = 0; ss < 3; ++ss) {
          const int s = c4 * 3 + ss;
          v8s ao = *(const v8s*)(O_lds + orow_clamped * M_O_LD + s * 32 + g * 8);
          #pragma unroll
          for (int t = 0; t < 6; ++t) {
            v8s bw = *(const v8s*)(w_lds + (16 * t + li) * WS_LD + ss * 32 + g * 8);
            pacc[t] = mfma16x16x32(ao, bw, pacc[t]);
          }
        }
      }
      __syncthreads();
    }
    if (wave < 7) {
      #pragma unroll
      for (int t = 0; t < 6; ++t) {
        #pragma unroll
        for (int j = 0; j < 4; ++j) {
          int row = 16 * wave + g * 4 + j;
          if (row < NTOK) {
            int col = cc * 96 + 16 * t + li;
            float v = pacc[t][j] + bproj[col];
            if (row == 0) out[OUT2 + (size_t)b * CDIM + col] = v;
            else          out[((size_t)b * 98 + (row - 1)) * CDIM + col] = v;
          }
        }
      }
    }
  }
}

extern "C" void kernel_launch(void* const* d_in, const int* in_sizes, int n_in,
                              void* d_out, int out_size, void* d_ws, size_t ws_size,
                              hipStream_t stream) {
  const float* x     = (const float*)d_in[0];
  const float* mask  = (const float*)d_in[1];
  const float* Wqkv  = (const float*)d_in[2];
  const float* rpb   = (const float*)d_in[3];
  const float* Wproj = (const float*)d_in[4];
  const float* bproj = (const float*)d_in[5];
  const int*   rpi   = (const int*)d_in[6];

  bf16*  WtQKV = (bf16*)((char*)d_ws + WT_QKV_OFF);
  bf16*  WtP   = (bf16*)((char*)d_ws + WT_P_OFF);
  float* BIAS  = (float*)((char*)d_ws + BIAS_OFF);
  bf16*  BMF   = (bf16*)((char*)d_ws + BMF_OFF);

  const bool full = (ws_size >= WS_FULL);
  const int prep_items = full ? PREP_W : PREP_BASE;   // BIAS only for MID/MONO
  prep_kernel<<<(prep_items + 255) / 256, 256, 0, stream>>>(
      Wqkv, Wproj, rpb, rpi, WtQKV, WtP, BIAS, full ? 0 : 1);

  if (full) {
    bf16* qkv2 = (bf16*)((char*)d_ws + QKV_OFF);
    k_qkv2<<<BMF_BLKS + 792 * 6, 512, 0, stream>>>(x, WtQKV, qkv2,
                                                   rpb, rpi, mask, BMF);
    k_attn<<<1024, 448, 0, stream>>>(BMF, qkv2);
    k2_proj2<<<792 * 2, 512, 0, stream>>>(qkv2, WtP, bproj, (float*)d_out);
  } else if (ws_size >= WS_MID) {
    bf16* O_ws = (bf16*)((char*)d_ws + O_WS_OFF);
    k1_attn<<<1024, 512, 0, stream>>>(x, mask, BIAS, WtQKV, O_ws);
    k2_proj<<<792 * 2, 512, 0, stream>>>(O_ws, WtP, bproj, (float*)d_out);
  } else {
    fused_mono<<<1024, 512, 0, stream>>>(x, mask, bproj, BIAS, WtQKV, WtP,
                                         (float*)d_out);
  }
}